// Round 1
// baseline (1735.344 us; speedup 1.0000x reference)
//
#include <hip/hip_runtime.h>

// ---------------------------------------------------------------------------
// ReparamGaussianMoE: D=1024, H=2048, E=8, N=4096, TAU=0.1
// All inputs fp32. Strategy: f16 MFMA (16x16x32) for all big GEMMs.
// Gate GEMM1 uses fp16 hi/lo split (K=3072) for fp32-class accuracy since
// softmax(z/0.1) amplifies logit error. v-path/m-path in plain fp16 (error
// ~2e-4 rms, budget ~1e-3).
// ---------------------------------------------------------------------------

typedef _Float16 f16x8 __attribute__((ext_vector_type(8)));
typedef float    f32x4 __attribute__((ext_vector_type(4)));

__device__ __forceinline__ void async_copy16(const void* g, void* l) {
  __builtin_amdgcn_global_load_lds(
      (const __attribute__((address_space(1))) void*)g,
      (__attribute__((address_space(3))) void*)l, 16, 0, 0);
}

// ---- conversion kernels ---------------------------------------------------

// x [4096][1024] f32 -> Ax [4096][3072] f16 laid out [hi | hi | lo]
__global__ __launch_bounds__(256) void split_x_kernel(
    const float* __restrict__ x, _Float16* __restrict__ Ax) {
  int idx = blockIdx.x * 256 + threadIdx.x;  // 4096*1024 threads
  int m = idx >> 10, k = idx & 1023;
  float v = x[idx];
  _Float16 hi = (_Float16)v;
  _Float16 lo = (_Float16)(v - (float)hi);
  _Float16* row = Ax + (size_t)m * 3072;
  row[k] = hi;
  row[k + 1024] = hi;
  row[k + 2048] = lo;
}

// Wg1 [1024][2048] f32 -> Wg1t [2048][3072] f16 laid out [hi | lo | hi]
__global__ __launch_bounds__(256) void split_transpose_wg1_kernel(
    const float* __restrict__ in, _Float16* __restrict__ out) {
  __shared__ float tile[64][65];
  int kb = blockIdx.y * 64, nb = blockIdx.x * 64;
  int c = threadIdx.x & 63, r0 = threadIdx.x >> 6;
#pragma unroll
  for (int i = 0; i < 16; ++i) {
    int r = r0 + i * 4;
    tile[r][c] = in[(size_t)(kb + r) * 2048 + nb + c];
  }
  __syncthreads();
#pragma unroll
  for (int i = 0; i < 16; ++i) {
    int rn = r0 + i * 4;
    float v = tile[c][rn];
    _Float16 hi = (_Float16)v;
    _Float16 lo = (_Float16)(v - (float)hi);
    _Float16* row = out + (size_t)(nb + rn) * 3072 + kb;
    row[c] = hi;
    row[c + 1024] = lo;
    row[c + 2048] = hi;
  }
}

// in [z][K][N] f32 -> out [z][N][K] f16 (transpose + convert)
__global__ __launch_bounds__(256) void transpose_f32_to_f16(
    const float* __restrict__ in, _Float16* __restrict__ out, int K, int N) {
  __shared__ float tile[64][65];
  size_t zo = (size_t)blockIdx.z * K * N;
  int kb = blockIdx.y * 64, nb = blockIdx.x * 64;
  int c = threadIdx.x & 63, r0 = threadIdx.x >> 6;
  const float* ip = in + zo + (size_t)kb * N + nb;
#pragma unroll
  for (int i = 0; i < 16; ++i) {
    int r = r0 + i * 4;
    tile[r][c] = ip[(size_t)r * N + c];
  }
  __syncthreads();
  _Float16* op = out + zo + (size_t)nb * K + kb;
#pragma unroll
  for (int i = 0; i < 16; ++i) {
    int rn = r0 + i * 4;
    op[(size_t)rn * K + c] = (_Float16)tile[c][rn];
  }
}

// ---- GEMM1: C = relu(A * Bt^T + bias), 128x128 tile, BK=32 ----------------
// A [4096][lda] f16 row-major, Bt [N][K] f16 row-major (K contiguous).
// blockIdx.z selects (B0,C0,bias0) vs (B1,C1,bias1).
template <typename OutT>
__global__ __launch_bounds__(256) void gemm1_kernel(
    const _Float16* __restrict__ A, int lda,
    const _Float16* __restrict__ B0, const _Float16* __restrict__ B1,
    OutT* __restrict__ C0, OutT* __restrict__ C1, int ldc,
    const float* __restrict__ bias0, const float* __restrict__ bias1, int K) {
  __shared__ _Float16 As[128 * 32];
  __shared__ _Float16 Bs[128 * 32];
  const int tid = threadIdx.x, lane = tid & 63, wid = tid >> 6;
  const _Float16* __restrict__ Bt = blockIdx.z ? B1 : B0;
  OutT* __restrict__ C = blockIdx.z ? C1 : C0;
  const float* __restrict__ bias = blockIdx.z ? bias1 : bias0;
  const int m0 = blockIdx.y * 128, n0 = blockIdx.x * 128;
  const int wm = (wid >> 1) * 64, wn = (wid & 1) * 64;
  const int lanelo = lane & 15, laneq = lane >> 4;
  f32x4 acc[4][4] = {};

  // staging geometry: 512 16B-chunks per tile; chunk c -> (row c>>2, col (c&3)*8)
  const int c0 = wid * 128 + lane, c1 = c0 + 64;
  const int ra0 = c0 >> 2, ca0 = (c0 & 3) * 8;
  const int ra1 = c1 >> 2, ca1 = (c1 & 3) * 8;
  _Float16* ldsA0 = As + (wid * 128 + 0) * 8;   // wave-uniform LDS bases
  _Float16* ldsA1 = As + (wid * 128 + 64) * 8;
  _Float16* ldsB0 = Bs + (wid * 128 + 0) * 8;
  _Float16* ldsB1 = Bs + (wid * 128 + 64) * 8;
  const _Float16* Arow0 = A + (size_t)(m0 + ra0) * lda + ca0;
  const _Float16* Arow1 = A + (size_t)(m0 + ra1) * lda + ca1;
  const _Float16* Brow0 = Bt + (size_t)(n0 + ra0) * K + ca0;
  const _Float16* Brow1 = Bt + (size_t)(n0 + ra1) * K + ca1;

  for (int k0 = 0; k0 < K; k0 += 32) {
    async_copy16(Arow0 + k0, ldsA0);
    async_copy16(Arow1 + k0, ldsA1);
    async_copy16(Brow0 + k0, ldsB0);
    async_copy16(Brow1 + k0, ldsB1);
    __syncthreads();
    f16x8 a[4], b[4];
#pragma unroll
    for (int i = 0; i < 4; ++i)
      a[i] = *reinterpret_cast<const f16x8*>(
          &As[(wm + i * 16 + lanelo) * 32 + laneq * 8]);
#pragma unroll
    for (int j = 0; j < 4; ++j)
      b[j] = *reinterpret_cast<const f16x8*>(
          &Bs[(wn + j * 16 + lanelo) * 32 + laneq * 8]);
#pragma unroll
    for (int i = 0; i < 4; ++i)
#pragma unroll
      for (int j = 0; j < 4; ++j)
        acc[i][j] =
            __builtin_amdgcn_mfma_f32_16x16x32_f16(a[i], b[j], acc[i][j], 0, 0, 0);
    __syncthreads();
  }

#pragma unroll
  for (int j = 0; j < 4; ++j) {
    const int n = n0 + wn + j * 16 + lanelo;
    const float bn = bias[n];
#pragma unroll
    for (int i = 0; i < 4; ++i) {
#pragma unroll
      for (int r = 0; r < 4; ++r) {
        const int m = m0 + wm + i * 16 + laneq * 4 + r;
        float v = acc[i][j][r] + bn;
        v = v > 0.f ? v : 0.f;
        C[(size_t)m * ldc + n] = (OutT)v;
      }
    }
  }
}

// ---- GEMM2 + combine: out (+)= w_e * (hm*Wm2+bm2 + eps*exp(0.5*(hv*Wv2+bv2)))
// 128x64 tile, two parallel MFMA accumulation streams (mu, lv). K=2048.
__global__ __launch_bounds__(256) void gemm2_combine_kernel(
    const _Float16* __restrict__ Am, const _Float16* __restrict__ Av,
    const _Float16* __restrict__ Bm, const _Float16* __restrict__ Bv,
    const float* __restrict__ biasm, const float* __restrict__ biasv,
    const float* __restrict__ epsE, const float* __restrict__ wE,
    float* __restrict__ out, const int accumulate) {
  __shared__ _Float16 Asm[128 * 32], Asv[128 * 32], Bsm[64 * 32], Bsv[64 * 32];
  const int tid = threadIdx.x, lane = tid & 63, wid = tid >> 6;
  const int m0 = blockIdx.y * 128, n0 = blockIdx.x * 64;
  const int wm = (wid >> 1) * 64, wn = (wid & 1) * 32;
  const int lanelo = lane & 15, laneq = lane >> 4;
  f32x4 accm[4][2] = {}, accv[4][2] = {};

  const int cA0 = wid * 128 + lane, cA1 = cA0 + 64;
  const int rA0 = cA0 >> 2, kA0 = (cA0 & 3) * 8;
  const int rA1 = cA1 >> 2, kA1 = (cA1 & 3) * 8;
  const int cB = wid * 64 + lane;
  const int rB = cB >> 2, kB = (cB & 3) * 8;
  const _Float16* am0 = Am + (size_t)(m0 + rA0) * 2048 + kA0;
  const _Float16* am1 = Am + (size_t)(m0 + rA1) * 2048 + kA1;
  const _Float16* av0 = Av + (size_t)(m0 + rA0) * 2048 + kA0;
  const _Float16* av1 = Av + (size_t)(m0 + rA1) * 2048 + kA1;
  const _Float16* bmp = Bm + (size_t)(n0 + rB) * 2048 + kB;
  const _Float16* bvp = Bv + (size_t)(n0 + rB) * 2048 + kB;
  _Float16* lAm0 = Asm + (wid * 128 + 0) * 8;
  _Float16* lAm1 = Asm + (wid * 128 + 64) * 8;
  _Float16* lAv0 = Asv + (wid * 128 + 0) * 8;
  _Float16* lAv1 = Asv + (wid * 128 + 64) * 8;
  _Float16* lBm = Bsm + (wid * 64) * 8;
  _Float16* lBv = Bsv + (wid * 64) * 8;

  for (int k0 = 0; k0 < 2048; k0 += 32) {
    async_copy16(am0 + k0, lAm0);
    async_copy16(am1 + k0, lAm1);
    async_copy16(av0 + k0, lAv0);
    async_copy16(av1 + k0, lAv1);
    async_copy16(bmp + k0, lBm);
    async_copy16(bvp + k0, lBv);
    __syncthreads();
    f16x8 am[4], av[4], bm[2], bv[2];
#pragma unroll
    for (int i = 0; i < 4; ++i) {
      am[i] = *reinterpret_cast<const f16x8*>(
          &Asm[(wm + i * 16 + lanelo) * 32 + laneq * 8]);
      av[i] = *reinterpret_cast<const f16x8*>(
          &Asv[(wm + i * 16 + lanelo) * 32 + laneq * 8]);
    }
#pragma unroll
    for (int j = 0; j < 2; ++j) {
      bm[j] = *reinterpret_cast<const f16x8*>(
          &Bsm[(wn + j * 16 + lanelo) * 32 + laneq * 8]);
      bv[j] = *reinterpret_cast<const f16x8*>(
          &Bsv[(wn + j * 16 + lanelo) * 32 + laneq * 8]);
    }
#pragma unroll
    for (int i = 0; i < 4; ++i)
#pragma unroll
      for (int j = 0; j < 2; ++j) {
        accm[i][j] =
            __builtin_amdgcn_mfma_f32_16x16x32_f16(am[i], bm[j], accm[i][j], 0, 0, 0);
        accv[i][j] =
            __builtin_amdgcn_mfma_f32_16x16x32_f16(av[i], bv[j], accv[i][j], 0, 0, 0);
      }
    __syncthreads();
  }

#pragma unroll
  for (int i = 0; i < 4; ++i) {
#pragma unroll
    for (int r = 0; r < 4; ++r) {
      const int m = m0 + wm + i * 16 + laneq * 4 + r;
      const float wgt = wE[(size_t)m * 8];
      const float* erow = epsE + (size_t)m * 8192;
      float* orow = out + (size_t)m * 1024;
#pragma unroll
      for (int j = 0; j < 2; ++j) {
        const int d = n0 + wn + j * 16 + lanelo;
        const float mu = accm[i][j][r] + biasm[d];
        const float lv = accv[i][j][r] + biasv[d];
        const float val = wgt * (mu + erow[d] * __expf(0.5f * lv));
        if (accumulate)
          orow[d] += val;
        else
          orow[d] = val;
      }
    }
  }
}

// ---- gate finish: logits = hg @ Wg2 + bg2; w = softmax((logits+gumbel)/tau)
__global__ __launch_bounds__(256) void gate_finish_kernel(
    const float* __restrict__ hg, const float* __restrict__ Wg2,
    const float* __restrict__ bg2, const float* __restrict__ gu,
    float* __restrict__ w) {
  const int lane = threadIdx.x & 63, wid = threadIdx.x >> 6;
  const int row = blockIdx.x * 4 + wid;
  const float* hrow = hg + (size_t)row * 2048;
  float acc[8] = {0.f, 0.f, 0.f, 0.f, 0.f, 0.f, 0.f, 0.f};
  for (int h = lane; h < 2048; h += 64) {
    const float hv = hrow[h];
    const float* wr = Wg2 + (size_t)h * 8;
#pragma unroll
    for (int e = 0; e < 8; ++e) acc[e] += hv * wr[e];
  }
#pragma unroll
  for (int off = 32; off > 0; off >>= 1) {
#pragma unroll
    for (int e = 0; e < 8; ++e) acc[e] += __shfl_down(acc[e], off);
  }
  if (lane == 0) {
    float z[8], zmax = -1e30f;
#pragma unroll
    for (int e = 0; e < 8; ++e) {
      const float u = gu[(size_t)row * 8 + e];
      const float g = -logf(-logf(u));  // accurate libm logs (softmax-sensitive)
      z[e] = (acc[e] + bg2[e] + g) / 0.1f;
      zmax = fmaxf(zmax, z[e]);
    }
    float s = 0.f;
#pragma unroll
    for (int e = 0; e < 8; ++e) {
      z[e] = __expf(z[e] - zmax);
      s += z[e];
    }
    const float inv = 1.f / s;
#pragma unroll
    for (int e = 0; e < 8; ++e) w[(size_t)row * 8 + e] = z[e] * inv;
  }
}

// ---------------------------------------------------------------------------

extern "C" void kernel_launch(void* const* d_in, const int* in_sizes, int n_in,
                              void* d_out, int out_size, void* d_ws,
                              size_t ws_size, hipStream_t stream) {
  const float* x = (const float*)d_in[0];
  const float* gu = (const float*)d_in[1];
  const float* eps = (const float*)d_in[2];
  const float* Wg1 = (const float*)d_in[3];
  const float* bg1 = (const float*)d_in[4];
  const float* Wg2 = (const float*)d_in[5];
  const float* bg2 = (const float*)d_in[6];
  const float* Wm1 = (const float*)d_in[7];
  const float* bm1 = (const float*)d_in[8];
  const float* Wm2 = (const float*)d_in[9];
  const float* bm2 = (const float*)d_in[10];
  const float* Wv1 = (const float*)d_in[11];
  const float* bv1 = (const float*)d_in[12];
  const float* Wv2 = (const float*)d_in[13];
  const float* bv2 = (const float*)d_in[14];
  float* out = (float*)d_out;

  char* ws = (char*)d_ws;
  size_t off = 0;
  auto alloc = [&](size_t bytes) -> void* {
    void* p = ws + off;
    off = (off + bytes + 255) & ~(size_t)255;
    return p;
  };
  _Float16* Ax = (_Float16*)alloc(4096UL * 3072 * 2);          // 24 MB
  _Float16* Wg1t = (_Float16*)alloc(2048UL * 3072 * 2);        // 12 MB
  _Float16* W1t = (_Float16*)alloc(16UL * 2048 * 1024 * 2);    // Wm1t[8],Wv1t[8]
  _Float16* W2t = (_Float16*)alloc(16UL * 1024 * 2048 * 2);    // Wm2t[8],Wv2t[8]
  float* hg = (float*)alloc(4096UL * 2048 * 4);                // 32 MB
  float* wbuf = (float*)alloc(4096UL * 8 * 4);
  _Float16* hm = (_Float16*)alloc(4096UL * 2048 * 2);          // 16 MB
  _Float16* hv = (_Float16*)alloc(4096UL * 2048 * 2);          // 16 MB

  // 1) conversions
  split_x_kernel<<<4096 * 1024 / 256, 256, 0, stream>>>(x, Ax);
  split_transpose_wg1_kernel<<<dim3(2048 / 64, 1024 / 64), 256, 0, stream>>>(Wg1, Wg1t);
  transpose_f32_to_f16<<<dim3(2048 / 64, 1024 / 64, 8), 256, 0, stream>>>(
      Wm1, W1t, 1024, 2048);
  transpose_f32_to_f16<<<dim3(2048 / 64, 1024 / 64, 8), 256, 0, stream>>>(
      Wv1, W1t + 8UL * 2048 * 1024, 1024, 2048);
  transpose_f32_to_f16<<<dim3(1024 / 64, 2048 / 64, 8), 256, 0, stream>>>(
      Wm2, W2t, 2048, 1024);
  transpose_f32_to_f16<<<dim3(1024 / 64, 2048 / 64, 8), 256, 0, stream>>>(
      Wv2, W2t + 8UL * 1024 * 2048, 2048, 1024);

  // 2) gate: hg = relu(x@Wg1+bg1) via split-fp16 (K=3072), then softmax weights
  gemm1_kernel<float><<<dim3(2048 / 128, 4096 / 128, 1), 256, 0, stream>>>(
      Ax, 3072, Wg1t, Wg1t, hg, hg, 2048, bg1, bg1, 3072);
  gate_finish_kernel<<<4096 / 4, 256, 0, stream>>>(hg, Wg2, bg2, gu, wbuf);

  // 3) experts: GEMM1 (m & v via grid.z) then fused GEMM2+combine
  for (int e = 0; e < 8; ++e) {
    gemm1_kernel<_Float16><<<dim3(2048 / 128, 4096 / 128, 2), 256, 0, stream>>>(
        Ax, 3072, W1t + (size_t)e * 2048 * 1024,
        W1t + (size_t)(8 + e) * 2048 * 1024, hm, hv, 2048, bm1 + e * 2048,
        bv1 + e * 2048, 1024);
    gemm2_combine_kernel<<<dim3(1024 / 64, 4096 / 128), 256, 0, stream>>>(
        hm, hv, W2t + (size_t)e * 1024 * 2048,
        W2t + (size_t)(8 + e) * 1024 * 2048, bm2 + e * 1024, bv2 + e * 1024,
        eps + (size_t)e * 1024, wbuf + e, out, e > 0);
  }
}

// Round 2
// 1467.905 us; speedup vs baseline: 1.1822x; 1.1822x over previous
//
#include <hip/hip_runtime.h>

// ---------------------------------------------------------------------------
// ReparamGaussianMoE: D=1024, H=2048, E=8, N=4096, TAU=0.1
// R1: batch the expert axis into grid.z (occupancy was 20%, 2 blocks/CU).
// gemm2 accumulates into out via unsafeAtomicAdd (f32 hw atomic).
// ---------------------------------------------------------------------------

typedef _Float16 f16x8 __attribute__((ext_vector_type(8)));
typedef float    f32x4 __attribute__((ext_vector_type(4)));

__device__ __forceinline__ void async_copy16(const void* g, void* l) {
  __builtin_amdgcn_global_load_lds(
      (const __attribute__((address_space(1))) void*)g,
      (__attribute__((address_space(3))) void*)l, 16, 0, 0);
}

// ---- conversion kernels ---------------------------------------------------

__global__ __launch_bounds__(256) void split_x_kernel(
    const float* __restrict__ x, _Float16* __restrict__ Ax) {
  int idx = blockIdx.x * 256 + threadIdx.x;
  int m = idx >> 10, k = idx & 1023;
  float v = x[idx];
  _Float16 hi = (_Float16)v;
  _Float16 lo = (_Float16)(v - (float)hi);
  _Float16* row = Ax + (size_t)m * 3072;
  row[k] = hi;
  row[k + 1024] = hi;
  row[k + 2048] = lo;
}

__global__ __launch_bounds__(256) void split_transpose_wg1_kernel(
    const float* __restrict__ in, _Float16* __restrict__ out) {
  __shared__ float tile[64][65];
  int kb = blockIdx.y * 64, nb = blockIdx.x * 64;
  int c = threadIdx.x & 63, r0 = threadIdx.x >> 6;
#pragma unroll
  for (int i = 0; i < 16; ++i) {
    int r = r0 + i * 4;
    tile[r][c] = in[(size_t)(kb + r) * 2048 + nb + c];
  }
  __syncthreads();
#pragma unroll
  for (int i = 0; i < 16; ++i) {
    int rn = r0 + i * 4;
    float v = tile[c][rn];
    _Float16 hi = (_Float16)v;
    _Float16 lo = (_Float16)(v - (float)hi);
    _Float16* row = out + (size_t)(nb + rn) * 3072 + kb;
    row[c] = hi;
    row[c + 1024] = lo;
    row[c + 2048] = hi;
  }
}

// in [z][K][N] f32 -> out [z][N][K] f16
__global__ __launch_bounds__(256) void transpose_f32_to_f16(
    const float* __restrict__ in, _Float16* __restrict__ out, int K, int N) {
  __shared__ float tile[64][65];
  size_t zo = (size_t)blockIdx.z * K * N;
  int kb = blockIdx.y * 64, nb = blockIdx.x * 64;
  int c = threadIdx.x & 63, r0 = threadIdx.x >> 6;
  const float* ip = in + zo + (size_t)kb * N + nb;
#pragma unroll
  for (int i = 0; i < 16; ++i) {
    int r = r0 + i * 4;
    tile[r][c] = ip[(size_t)r * N + c];
  }
  __syncthreads();
  _Float16* op = out + zo + (size_t)nb * K + kb;
#pragma unroll
  for (int i = 0; i < 16; ++i) {
    int rn = r0 + i * 4;
    op[(size_t)rn * K + c] = (_Float16)tile[c][rn];
  }
}

__global__ __launch_bounds__(256) void zero_out_kernel(float4* __restrict__ p) {
  p[blockIdx.x * 256 + threadIdx.x] = float4{0.f, 0.f, 0.f, 0.f};
}

// ---- gate GEMM: hg = relu(Ax @ Wg1t^T + bg1), 128x128 tile, K=3072 --------
__global__ __launch_bounds__(256) void gate_gemm1_kernel(
    const _Float16* __restrict__ A, const _Float16* __restrict__ Bt,
    float* __restrict__ C, const float* __restrict__ bias) {
  __shared__ _Float16 As[128 * 32];
  __shared__ _Float16 Bs[128 * 32];
  const int tid = threadIdx.x, lane = tid & 63, wid = tid >> 6;
  const int m0 = blockIdx.y * 128, n0 = blockIdx.x * 128;
  const int wm = (wid >> 1) * 64, wn = (wid & 1) * 64;
  const int lanelo = lane & 15, laneq = lane >> 4;
  const int K = 3072, lda = 3072, ldc = 2048;
  f32x4 acc[4][4] = {};

  const int c0 = wid * 128 + lane, c1 = c0 + 64;
  const int ra0 = c0 >> 2, ca0 = (c0 & 3) * 8;
  const int ra1 = c1 >> 2, ca1 = (c1 & 3) * 8;
  _Float16* ldsA0 = As + (wid * 128 + 0) * 8;
  _Float16* ldsA1 = As + (wid * 128 + 64) * 8;
  _Float16* ldsB0 = Bs + (wid * 128 + 0) * 8;
  _Float16* ldsB1 = Bs + (wid * 128 + 64) * 8;
  const _Float16* Arow0 = A + (size_t)(m0 + ra0) * lda + ca0;
  const _Float16* Arow1 = A + (size_t)(m0 + ra1) * lda + ca1;
  const _Float16* Brow0 = Bt + (size_t)(n0 + ra0) * K + ca0;
  const _Float16* Brow1 = Bt + (size_t)(n0 + ra1) * K + ca1;

  for (int k0 = 0; k0 < K; k0 += 32) {
    async_copy16(Arow0 + k0, ldsA0);
    async_copy16(Arow1 + k0, ldsA1);
    async_copy16(Brow0 + k0, ldsB0);
    async_copy16(Brow1 + k0, ldsB1);
    __syncthreads();
    f16x8 a[4], b[4];
#pragma unroll
    for (int i = 0; i < 4; ++i)
      a[i] = *reinterpret_cast<const f16x8*>(
          &As[(wm + i * 16 + lanelo) * 32 + laneq * 8]);
#pragma unroll
    for (int j = 0; j < 4; ++j)
      b[j] = *reinterpret_cast<const f16x8*>(
          &Bs[(wn + j * 16 + lanelo) * 32 + laneq * 8]);
#pragma unroll
    for (int i = 0; i < 4; ++i)
#pragma unroll
      for (int j = 0; j < 4; ++j)
        acc[i][j] =
            __builtin_amdgcn_mfma_f32_16x16x32_f16(a[i], b[j], acc[i][j], 0, 0, 0);
    __syncthreads();
  }

#pragma unroll
  for (int j = 0; j < 4; ++j) {
    const int n = n0 + wn + j * 16 + lanelo;
    const float bn = bias[n];
#pragma unroll
    for (int i = 0; i < 4; ++i) {
#pragma unroll
      for (int r = 0; r < 4; ++r) {
        const int m = m0 + wm + i * 16 + laneq * 4 + r;
        float v = acc[i][j][r] + bn;
        C[(size_t)m * ldc + n] = v > 0.f ? v : 0.f;
      }
    }
  }
}

// ---- expert GEMM1 (batched over z = 2*local_e + {m,v}): hm/hv = relu(x@W1+b)
__global__ __launch_bounds__(256) void expert_gemm1_kernel(
    const _Float16* __restrict__ A, const _Float16* __restrict__ W1t,
    _Float16* __restrict__ hm, _Float16* __restrict__ hv,
    const float* __restrict__ bm1, const float* __restrict__ bv1, int e0) {
  __shared__ _Float16 As[128 * 32];
  __shared__ _Float16 Bs[128 * 32];
  const int tid = threadIdx.x, lane = tid & 63, wid = tid >> 6;
  const int s = blockIdx.z & 1, le = blockIdx.z >> 1, e = e0 + le;
  const _Float16* __restrict__ Bt = W1t + (size_t)(s * 8 + e) * 2048 * 1024;
  _Float16* __restrict__ C = (s ? hv : hm) + (size_t)le * 4096 * 2048;
  const float* __restrict__ bias = (s ? bv1 : bm1) + e * 2048;
  const int m0 = blockIdx.y * 128, n0 = blockIdx.x * 128;
  const int wm = (wid >> 1) * 64, wn = (wid & 1) * 64;
  const int lanelo = lane & 15, laneq = lane >> 4;
  const int K = 1024, lda = 3072, ldc = 2048;
  f32x4 acc[4][4] = {};

  const int c0 = wid * 128 + lane, c1 = c0 + 64;
  const int ra0 = c0 >> 2, ca0 = (c0 & 3) * 8;
  const int ra1 = c1 >> 2, ca1 = (c1 & 3) * 8;
  _Float16* ldsA0 = As + (wid * 128 + 0) * 8;
  _Float16* ldsA1 = As + (wid * 128 + 64) * 8;
  _Float16* ldsB0 = Bs + (wid * 128 + 0) * 8;
  _Float16* ldsB1 = Bs + (wid * 128 + 64) * 8;
  const _Float16* Arow0 = A + (size_t)(m0 + ra0) * lda + ca0;
  const _Float16* Arow1 = A + (size_t)(m0 + ra1) * lda + ca1;
  const _Float16* Brow0 = Bt + (size_t)(n0 + ra0) * K + ca0;
  const _Float16* Brow1 = Bt + (size_t)(n0 + ra1) * K + ca1;

  for (int k0 = 0; k0 < K; k0 += 32) {
    async_copy16(Arow0 + k0, ldsA0);
    async_copy16(Arow1 + k0, ldsA1);
    async_copy16(Brow0 + k0, ldsB0);
    async_copy16(Brow1 + k0, ldsB1);
    __syncthreads();
    f16x8 a[4], b[4];
#pragma unroll
    for (int i = 0; i < 4; ++i)
      a[i] = *reinterpret_cast<const f16x8*>(
          &As[(wm + i * 16 + lanelo) * 32 + laneq * 8]);
#pragma unroll
    for (int j = 0; j < 4; ++j)
      b[j] = *reinterpret_cast<const f16x8*>(
          &Bs[(wn + j * 16 + lanelo) * 32 + laneq * 8]);
#pragma unroll
    for (int i = 0; i < 4; ++i)
#pragma unroll
      for (int j = 0; j < 4; ++j)
        acc[i][j] =
            __builtin_amdgcn_mfma_f32_16x16x32_f16(a[i], b[j], acc[i][j], 0, 0, 0);
    __syncthreads();
  }

#pragma unroll
  for (int j = 0; j < 4; ++j) {
    const int n = n0 + wn + j * 16 + lanelo;
    const float bn = bias[n];
#pragma unroll
    for (int i = 0; i < 4; ++i) {
#pragma unroll
      for (int r = 0; r < 4; ++r) {
        const int m = m0 + wm + i * 16 + laneq * 4 + r;
        float v = acc[i][j][r] + bn;
        C[(size_t)m * ldc + n] = (_Float16)(v > 0.f ? v : 0.f);
      }
    }
  }
}

// ---- GEMM2 + combine (batched over z = local expert) ----------------------
// out += w_e * (hm@Wm2+bm2 + eps_e * exp(0.5*(hv@Wv2+bv2)))  via f32 atomics
__global__ __launch_bounds__(256) void gemm2_combine_kernel(
    const _Float16* __restrict__ hm, const _Float16* __restrict__ hv,
    const _Float16* __restrict__ W2t, const float* __restrict__ bm2,
    const float* __restrict__ bv2, const float* __restrict__ eps,
    const float* __restrict__ w, float* __restrict__ out, int e0) {
  __shared__ _Float16 Asm[128 * 32], Asv[128 * 32], Bsm[64 * 32], Bsv[64 * 32];
  const int tid = threadIdx.x, lane = tid & 63, wid = tid >> 6;
  const int le = blockIdx.z, e = e0 + le;
  const _Float16* __restrict__ Am = hm + (size_t)le * 4096 * 2048;
  const _Float16* __restrict__ Av = hv + (size_t)le * 4096 * 2048;
  const _Float16* __restrict__ Bm = W2t + (size_t)e * 1024 * 2048;
  const _Float16* __restrict__ Bv = W2t + (size_t)(8 + e) * 1024 * 2048;
  const float* __restrict__ biasm = bm2 + e * 1024;
  const float* __restrict__ biasv = bv2 + e * 1024;
  const float* __restrict__ epsE = eps + e * 1024;
  const float* __restrict__ wE = w + e;
  const int m0 = blockIdx.y * 128, n0 = blockIdx.x * 64;
  const int wm = (wid >> 1) * 64, wn = (wid & 1) * 32;
  const int lanelo = lane & 15, laneq = lane >> 4;
  f32x4 accm[4][2] = {}, accv[4][2] = {};

  const int cA0 = wid * 128 + lane, cA1 = cA0 + 64;
  const int rA0 = cA0 >> 2, kA0 = (cA0 & 3) * 8;
  const int rA1 = cA1 >> 2, kA1 = (cA1 & 3) * 8;
  const int cB = wid * 64 + lane;
  const int rB = cB >> 2, kB = (cB & 3) * 8;
  const _Float16* am0 = Am + (size_t)(m0 + rA0) * 2048 + kA0;
  const _Float16* am1 = Am + (size_t)(m0 + rA1) * 2048 + kA1;
  const _Float16* av0 = Av + (size_t)(m0 + rA0) * 2048 + kA0;
  const _Float16* av1 = Av + (size_t)(m0 + rA1) * 2048 + kA1;
  const _Float16* bmp = Bm + (size_t)(n0 + rB) * 2048 + kB;
  const _Float16* bvp = Bv + (size_t)(n0 + rB) * 2048 + kB;
  _Float16* lAm0 = Asm + (wid * 128 + 0) * 8;
  _Float16* lAm1 = Asm + (wid * 128 + 64) * 8;
  _Float16* lAv0 = Asv + (wid * 128 + 0) * 8;
  _Float16* lAv1 = Asv + (wid * 128 + 64) * 8;
  _Float16* lBm = Bsm + (wid * 64) * 8;
  _Float16* lBv = Bsv + (wid * 64) * 8;

  for (int k0 = 0; k0 < 2048; k0 += 32) {
    async_copy16(am0 + k0, lAm0);
    async_copy16(am1 + k0, lAm1);
    async_copy16(av0 + k0, lAv0);
    async_copy16(av1 + k0, lAv1);
    async_copy16(bmp + k0, lBm);
    async_copy16(bvp + k0, lBv);
    __syncthreads();
    f16x8 am[4], av[4], bm[2], bv[2];
#pragma unroll
    for (int i = 0; i < 4; ++i) {
      am[i] = *reinterpret_cast<const f16x8*>(
          &Asm[(wm + i * 16 + lanelo) * 32 + laneq * 8]);
      av[i] = *reinterpret_cast<const f16x8*>(
          &Asv[(wm + i * 16 + lanelo) * 32 + laneq * 8]);
    }
#pragma unroll
    for (int j = 0; j < 2; ++j) {
      bm[j] = *reinterpret_cast<const f16x8*>(
          &Bsm[(wn + j * 16 + lanelo) * 32 + laneq * 8]);
      bv[j] = *reinterpret_cast<const f16x8*>(
          &Bsv[(wn + j * 16 + lanelo) * 32 + laneq * 8]);
    }
#pragma unroll
    for (int i = 0; i < 4; ++i)
#pragma unroll
      for (int j = 0; j < 2; ++j) {
        accm[i][j] =
            __builtin_amdgcn_mfma_f32_16x16x32_f16(am[i], bm[j], accm[i][j], 0, 0, 0);
        accv[i][j] =
            __builtin_amdgcn_mfma_f32_16x16x32_f16(av[i], bv[j], accv[i][j], 0, 0, 0);
      }
    __syncthreads();
  }

#pragma unroll
  for (int i = 0; i < 4; ++i) {
#pragma unroll
    for (int r = 0; r < 4; ++r) {
      const int m = m0 + wm + i * 16 + laneq * 4 + r;
      const float wgt = wE[(size_t)m * 8];
      const float* erow = epsE + (size_t)m * 8192;
      float* orow = out + (size_t)m * 1024;
#pragma unroll
      for (int j = 0; j < 2; ++j) {
        const int d = n0 + wn + j * 16 + lanelo;
        const float mu = accm[i][j][r] + biasm[d];
        const float lv = accv[i][j][r] + biasv[d];
        unsafeAtomicAdd(&orow[d], wgt * (mu + erow[d] * __expf(0.5f * lv)));
      }
    }
  }
}

// ---- gate finish ----------------------------------------------------------
__global__ __launch_bounds__(256) void gate_finish_kernel(
    const float* __restrict__ hg, const float* __restrict__ Wg2,
    const float* __restrict__ bg2, const float* __restrict__ gu,
    float* __restrict__ w) {
  const int lane = threadIdx.x & 63, wid = threadIdx.x >> 6;
  const int row = blockIdx.x * 4 + wid;
  const float* hrow = hg + (size_t)row * 2048;
  float acc[8] = {0.f, 0.f, 0.f, 0.f, 0.f, 0.f, 0.f, 0.f};
  for (int h = lane; h < 2048; h += 64) {
    const float hv = hrow[h];
    const float* wr = Wg2 + (size_t)h * 8;
#pragma unroll
    for (int e = 0; e < 8; ++e) acc[e] += hv * wr[e];
  }
#pragma unroll
  for (int off = 32; off > 0; off >>= 1) {
#pragma unroll
    for (int e = 0; e < 8; ++e) acc[e] += __shfl_down(acc[e], off);
  }
  if (lane == 0) {
    float z[8], zmax = -1e30f;
#pragma unroll
    for (int e = 0; e < 8; ++e) {
      const float u = gu[(size_t)row * 8 + e];
      const float g = -logf(-logf(u));
      z[e] = (acc[e] + bg2[e] + g) / 0.1f;
      zmax = fmaxf(zmax, z[e]);
    }
    float s = 0.f;
#pragma unroll
    for (int e = 0; e < 8; ++e) {
      z[e] = __expf(z[e] - zmax);
      s += z[e];
    }
    const float inv = 1.f / s;
#pragma unroll
    for (int e = 0; e < 8; ++e) w[(size_t)row * 8 + e] = z[e] * inv;
  }
}

// ---------------------------------------------------------------------------

extern "C" void kernel_launch(void* const* d_in, const int* in_sizes, int n_in,
                              void* d_out, int out_size, void* d_ws,
                              size_t ws_size, hipStream_t stream) {
  const float* x = (const float*)d_in[0];
  const float* gu = (const float*)d_in[1];
  const float* eps = (const float*)d_in[2];
  const float* Wg1 = (const float*)d_in[3];
  const float* bg1 = (const float*)d_in[4];
  const float* Wg2 = (const float*)d_in[5];
  const float* bg2 = (const float*)d_in[6];
  const float* Wm1 = (const float*)d_in[7];
  const float* bm1 = (const float*)d_in[8];
  const float* Wm2 = (const float*)d_in[9];
  const float* bm2 = (const float*)d_in[10];
  const float* Wv1 = (const float*)d_in[11];
  const float* bv1 = (const float*)d_in[12];
  const float* Wv2 = (const float*)d_in[13];
  const float* bv2 = (const float*)d_in[14];
  float* out = (float*)d_out;

  char* ws = (char*)d_ws;
  size_t off = 0;
  auto alloc = [&](size_t bytes) -> void* {
    void* p = ws + off;
    off = (off + bytes + 255) & ~(size_t)255;
    return p;
  };
  _Float16* Ax = (_Float16*)alloc(4096UL * 3072 * 2);        // 24 MB
  _Float16* Wg1t = (_Float16*)alloc(2048UL * 3072 * 2);      // 12 MB
  _Float16* W1t = (_Float16*)alloc(16UL * 2048 * 1024 * 2);  // 64 MB
  _Float16* W2t = (_Float16*)alloc(16UL * 1024 * 2048 * 2);  // 64 MB
  float* hg = (float*)alloc(4096UL * 2048 * 4);              // 32 MB
  float* wbuf = (float*)alloc(4096UL * 8 * 4);

  // expert h-buffers: as many 16 MB hm/hv pairs as the workspace allows
  const size_t per = 4096UL * 2048 * 2;  // 16 MB, 256-aligned
  size_t remain = (ws_size > off) ? (ws_size - off) : 0;
  int g = (int)(remain / (2 * per));
  if (g > 8) g = 8;
  if (g < 1) g = 1;  // ws_size >= 239 MB observed; g>=1 always holds
  _Float16* hm = (_Float16*)alloc((size_t)g * per);
  _Float16* hv = (_Float16*)alloc((size_t)g * per);

  // 1) conversions + out zero-init
  zero_out_kernel<<<4096, 256, 0, stream>>>((float4*)out);
  split_x_kernel<<<4096 * 1024 / 256, 256, 0, stream>>>(x, Ax);
  split_transpose_wg1_kernel<<<dim3(2048 / 64, 1024 / 64), 256, 0, stream>>>(Wg1, Wg1t);
  transpose_f32_to_f16<<<dim3(2048 / 64, 1024 / 64, 8), 256, 0, stream>>>(
      Wm1, W1t, 1024, 2048);
  transpose_f32_to_f16<<<dim3(2048 / 64, 1024 / 64, 8), 256, 0, stream>>>(
      Wv1, W1t + 8UL * 2048 * 1024, 1024, 2048);
  transpose_f32_to_f16<<<dim3(1024 / 64, 2048 / 64, 8), 256, 0, stream>>>(
      Wm2, W2t, 2048, 1024);
  transpose_f32_to_f16<<<dim3(1024 / 64, 2048 / 64, 8), 256, 0, stream>>>(
      Wv2, W2t + 8UL * 1024 * 2048, 2048, 1024);

  // 2) gate
  gate_gemm1_kernel<<<dim3(2048 / 128, 4096 / 128), 256, 0, stream>>>(
      Ax, Wg1t, hg, bg1);
  gate_finish_kernel<<<4096 / 4, 256, 0, stream>>>(hg, Wg2, bg2, gu, wbuf);

  // 3) experts, batched over grid.z in groups of g
  for (int e0 = 0; e0 < 8; e0 += g) {
    const int ge = (8 - e0) < g ? (8 - e0) : g;
    expert_gemm1_kernel<<<dim3(2048 / 128, 4096 / 128, 2 * ge), 256, 0, stream>>>(
        Ax, W1t, hm, hv, bm1, bv1, e0);
    gemm2_combine_kernel<<<dim3(1024 / 64, 4096 / 128, ge), 256, 0, stream>>>(
        hm, hv, W2t, bm2, bv2, eps, wbuf, out, e0);
  }
}

// Round 3
// 1412.232 us; speedup vs baseline: 1.2288x; 1.0394x over previous
//
#include <hip/hip_runtime.h>

// ---------------------------------------------------------------------------
// ReparamGaussianMoE: D=1024, H=2048, E=8, N=4096, TAU=0.1
// R2: gemm2 restructured as a pure 128x128-tile GEMM batched over
// z=(expert,stream); the combine decomposes as out += w*mu  and
// out += w*eps*exp(0.5*lv), each applied in the owning block's epilogue via
// f32 hw atomics. Cuts LDS reads/MFMA from 0.75 to 0.5 and halves A re-reads.
// ---------------------------------------------------------------------------

typedef _Float16 f16x8 __attribute__((ext_vector_type(8)));
typedef float    f32x4 __attribute__((ext_vector_type(4)));

__device__ __forceinline__ void async_copy16(const void* g, void* l) {
  __builtin_amdgcn_global_load_lds(
      (const __attribute__((address_space(1))) void*)g,
      (__attribute__((address_space(3))) void*)l, 16, 0, 0);
}

// ---- conversion kernels ---------------------------------------------------

__global__ __launch_bounds__(256) void split_x_kernel(
    const float* __restrict__ x, _Float16* __restrict__ Ax) {
  int idx = blockIdx.x * 256 + threadIdx.x;
  int m = idx >> 10, k = idx & 1023;
  float v = x[idx];
  _Float16 hi = (_Float16)v;
  _Float16 lo = (_Float16)(v - (float)hi);
  _Float16* row = Ax + (size_t)m * 3072;
  row[k] = hi;
  row[k + 1024] = hi;
  row[k + 2048] = lo;
}

__global__ __launch_bounds__(256) void split_transpose_wg1_kernel(
    const float* __restrict__ in, _Float16* __restrict__ out) {
  __shared__ float tile[64][65];
  int kb = blockIdx.y * 64, nb = blockIdx.x * 64;
  int c = threadIdx.x & 63, r0 = threadIdx.x >> 6;
#pragma unroll
  for (int i = 0; i < 16; ++i) {
    int r = r0 + i * 4;
    tile[r][c] = in[(size_t)(kb + r) * 2048 + nb + c];
  }
  __syncthreads();
#pragma unroll
  for (int i = 0; i < 16; ++i) {
    int rn = r0 + i * 4;
    float v = tile[c][rn];
    _Float16 hi = (_Float16)v;
    _Float16 lo = (_Float16)(v - (float)hi);
    _Float16* row = out + (size_t)(nb + rn) * 3072 + kb;
    row[c] = hi;
    row[c + 1024] = lo;
    row[c + 2048] = hi;
  }
}

// in [z][K][N] f32 -> out [z][N][K] f16
__global__ __launch_bounds__(256) void transpose_f32_to_f16(
    const float* __restrict__ in, _Float16* __restrict__ out, int K, int N) {
  __shared__ float tile[64][65];
  size_t zo = (size_t)blockIdx.z * K * N;
  int kb = blockIdx.y * 64, nb = blockIdx.x * 64;
  int c = threadIdx.x & 63, r0 = threadIdx.x >> 6;
  const float* ip = in + zo + (size_t)kb * N + nb;
#pragma unroll
  for (int i = 0; i < 16; ++i) {
    int r = r0 + i * 4;
    tile[r][c] = ip[(size_t)r * N + c];
  }
  __syncthreads();
  _Float16* op = out + zo + (size_t)nb * K + kb;
#pragma unroll
  for (int i = 0; i < 16; ++i) {
    int rn = r0 + i * 4;
    op[(size_t)rn * K + c] = (_Float16)tile[c][rn];
  }
}

__global__ __launch_bounds__(256) void zero_out_kernel(float4* __restrict__ p) {
  p[blockIdx.x * 256 + threadIdx.x] = float4{0.f, 0.f, 0.f, 0.f};
}

// ---- gate GEMM: hg = relu(Ax @ Wg1t^T + bg1), 128x128 tile, K=3072 --------
__global__ __launch_bounds__(256) void gate_gemm1_kernel(
    const _Float16* __restrict__ A, const _Float16* __restrict__ Bt,
    float* __restrict__ C, const float* __restrict__ bias) {
  __shared__ _Float16 As[128 * 32];
  __shared__ _Float16 Bs[128 * 32];
  const int tid = threadIdx.x, lane = tid & 63, wid = tid >> 6;
  const int m0 = blockIdx.y * 128, n0 = blockIdx.x * 128;
  const int wm = (wid >> 1) * 64, wn = (wid & 1) * 64;
  const int lanelo = lane & 15, laneq = lane >> 4;
  const int K = 3072, lda = 3072, ldc = 2048;
  f32x4 acc[4][4] = {};

  const int c0 = wid * 128 + lane, c1 = c0 + 64;
  const int ra0 = c0 >> 2, ca0 = (c0 & 3) * 8;
  const int ra1 = c1 >> 2, ca1 = (c1 & 3) * 8;
  _Float16* ldsA0 = As + (wid * 128 + 0) * 8;
  _Float16* ldsA1 = As + (wid * 128 + 64) * 8;
  _Float16* ldsB0 = Bs + (wid * 128 + 0) * 8;
  _Float16* ldsB1 = Bs + (wid * 128 + 64) * 8;
  const _Float16* Arow0 = A + (size_t)(m0 + ra0) * lda + ca0;
  const _Float16* Arow1 = A + (size_t)(m0 + ra1) * lda + ca1;
  const _Float16* Brow0 = Bt + (size_t)(n0 + ra0) * K + ca0;
  const _Float16* Brow1 = Bt + (size_t)(n0 + ra1) * K + ca1;

  for (int k0 = 0; k0 < K; k0 += 32) {
    async_copy16(Arow0 + k0, ldsA0);
    async_copy16(Arow1 + k0, ldsA1);
    async_copy16(Brow0 + k0, ldsB0);
    async_copy16(Brow1 + k0, ldsB1);
    __syncthreads();
    f16x8 a[4], b[4];
#pragma unroll
    for (int i = 0; i < 4; ++i)
      a[i] = *reinterpret_cast<const f16x8*>(
          &As[(wm + i * 16 + lanelo) * 32 + laneq * 8]);
#pragma unroll
    for (int j = 0; j < 4; ++j)
      b[j] = *reinterpret_cast<const f16x8*>(
          &Bs[(wn + j * 16 + lanelo) * 32 + laneq * 8]);
#pragma unroll
    for (int i = 0; i < 4; ++i)
#pragma unroll
      for (int j = 0; j < 4; ++j)
        acc[i][j] =
            __builtin_amdgcn_mfma_f32_16x16x32_f16(a[i], b[j], acc[i][j], 0, 0, 0);
    __syncthreads();
  }

#pragma unroll
  for (int j = 0; j < 4; ++j) {
    const int n = n0 + wn + j * 16 + lanelo;
    const float bn = bias[n];
#pragma unroll
    for (int i = 0; i < 4; ++i) {
#pragma unroll
      for (int r = 0; r < 4; ++r) {
        const int m = m0 + wm + i * 16 + laneq * 4 + r;
        float v = acc[i][j][r] + bn;
        C[(size_t)m * ldc + n] = v > 0.f ? v : 0.f;
      }
    }
  }
}

// ---- expert GEMM1 (batched over z = 2*local_e + {m,v}): hm/hv = relu(x@W1+b)
__global__ __launch_bounds__(256) void expert_gemm1_kernel(
    const _Float16* __restrict__ A, const _Float16* __restrict__ W1t,
    _Float16* __restrict__ hm, _Float16* __restrict__ hv,
    const float* __restrict__ bm1, const float* __restrict__ bv1) {
  __shared__ _Float16 As[128 * 32];
  __shared__ _Float16 Bs[128 * 32];
  const int tid = threadIdx.x, lane = tid & 63, wid = tid >> 6;
  const int s = blockIdx.z & 1, e = blockIdx.z >> 1;
  const _Float16* __restrict__ Bt = W1t + (size_t)(s * 8 + e) * 2048 * 1024;
  _Float16* __restrict__ C = (s ? hv : hm) + (size_t)e * 4096 * 2048;
  const float* __restrict__ bias = (s ? bv1 : bm1) + e * 2048;
  const int m0 = blockIdx.y * 128, n0 = blockIdx.x * 128;
  const int wm = (wid >> 1) * 64, wn = (wid & 1) * 64;
  const int lanelo = lane & 15, laneq = lane >> 4;
  const int K = 1024, lda = 3072, ldc = 2048;
  f32x4 acc[4][4] = {};

  const int c0 = wid * 128 + lane, c1 = c0 + 64;
  const int ra0 = c0 >> 2, ca0 = (c0 & 3) * 8;
  const int ra1 = c1 >> 2, ca1 = (c1 & 3) * 8;
  _Float16* ldsA0 = As + (wid * 128 + 0) * 8;
  _Float16* ldsA1 = As + (wid * 128 + 64) * 8;
  _Float16* ldsB0 = Bs + (wid * 128 + 0) * 8;
  _Float16* ldsB1 = Bs + (wid * 128 + 64) * 8;
  const _Float16* Arow0 = A + (size_t)(m0 + ra0) * lda + ca0;
  const _Float16* Arow1 = A + (size_t)(m0 + ra1) * lda + ca1;
  const _Float16* Brow0 = Bt + (size_t)(n0 + ra0) * K + ca0;
  const _Float16* Brow1 = Bt + (size_t)(n0 + ra1) * K + ca1;

  for (int k0 = 0; k0 < K; k0 += 32) {
    async_copy16(Arow0 + k0, ldsA0);
    async_copy16(Arow1 + k0, ldsA1);
    async_copy16(Brow0 + k0, ldsB0);
    async_copy16(Brow1 + k0, ldsB1);
    __syncthreads();
    f16x8 a[4], b[4];
#pragma unroll
    for (int i = 0; i < 4; ++i)
      a[i] = *reinterpret_cast<const f16x8*>(
          &As[(wm + i * 16 + lanelo) * 32 + laneq * 8]);
#pragma unroll
    for (int j = 0; j < 4; ++j)
      b[j] = *reinterpret_cast<const f16x8*>(
          &Bs[(wn + j * 16 + lanelo) * 32 + laneq * 8]);
#pragma unroll
    for (int i = 0; i < 4; ++i)
#pragma unroll
      for (int j = 0; j < 4; ++j)
        acc[i][j] =
            __builtin_amdgcn_mfma_f32_16x16x32_f16(a[i], b[j], acc[i][j], 0, 0, 0);
    __syncthreads();
  }

#pragma unroll
  for (int j = 0; j < 4; ++j) {
    const int n = n0 + wn + j * 16 + lanelo;
    const float bn = bias[n];
#pragma unroll
    for (int i = 0; i < 4; ++i) {
#pragma unroll
      for (int r = 0; r < 4; ++r) {
        const int m = m0 + wm + i * 16 + laneq * 4 + r;
        float v = acc[i][j][r] + bn;
        C[(size_t)m * ldc + n] = (_Float16)(v > 0.f ? v : 0.f);
      }
    }
  }
}

// ---- GEMM2 + combine: 128x128 tile, z = expert*2 + stream ------------------
// stream 0: out[m][d] += w[m][e] * (acc + bm2[e][d])
// stream 1: out[m][d] += w[m][e] * eps[m][e][d] * exp(0.5*(acc + bv2[e][d]))
__global__ __launch_bounds__(256) void gemm2_combine_kernel(
    const _Float16* __restrict__ hm, const _Float16* __restrict__ hv,
    const _Float16* __restrict__ W2t, const float* __restrict__ bm2,
    const float* __restrict__ bv2, const float* __restrict__ eps,
    const float* __restrict__ w, float* __restrict__ out) {
  __shared__ _Float16 As[128 * 32];
  __shared__ _Float16 Bs[128 * 32];
  const int tid = threadIdx.x, lane = tid & 63, wid = tid >> 6;
  const int s = blockIdx.z & 1, e = blockIdx.z >> 1;
  const _Float16* __restrict__ A = (s ? hv : hm) + (size_t)e * 4096 * 2048;
  const _Float16* __restrict__ Bt = W2t + (size_t)(s * 8 + e) * 1024 * 2048;
  const float* __restrict__ bias = (s ? bv2 : bm2) + e * 1024;
  const float* __restrict__ epsE = eps + e * 1024;
  const int m0 = blockIdx.y * 128, n0 = blockIdx.x * 128;
  const int wm = (wid >> 1) * 64, wn = (wid & 1) * 64;
  const int lanelo = lane & 15, laneq = lane >> 4;
  const int K = 2048, lda = 2048;
  f32x4 acc[4][4] = {};

  const int c0 = wid * 128 + lane, c1 = c0 + 64;
  const int ra0 = c0 >> 2, ca0 = (c0 & 3) * 8;
  const int ra1 = c1 >> 2, ca1 = (c1 & 3) * 8;
  _Float16* ldsA0 = As + (wid * 128 + 0) * 8;
  _Float16* ldsA1 = As + (wid * 128 + 64) * 8;
  _Float16* ldsB0 = Bs + (wid * 128 + 0) * 8;
  _Float16* ldsB1 = Bs + (wid * 128 + 64) * 8;
  const _Float16* Arow0 = A + (size_t)(m0 + ra0) * lda + ca0;
  const _Float16* Arow1 = A + (size_t)(m0 + ra1) * lda + ca1;
  const _Float16* Brow0 = Bt + (size_t)(n0 + ra0) * K + ca0;
  const _Float16* Brow1 = Bt + (size_t)(n0 + ra1) * K + ca1;

  for (int k0 = 0; k0 < K; k0 += 32) {
    async_copy16(Arow0 + k0, ldsA0);
    async_copy16(Arow1 + k0, ldsA1);
    async_copy16(Brow0 + k0, ldsB0);
    async_copy16(Brow1 + k0, ldsB1);
    __syncthreads();
    f16x8 a[4], b[4];
#pragma unroll
    for (int i = 0; i < 4; ++i)
      a[i] = *reinterpret_cast<const f16x8*>(
          &As[(wm + i * 16 + lanelo) * 32 + laneq * 8]);
#pragma unroll
    for (int j = 0; j < 4; ++j)
      b[j] = *reinterpret_cast<const f16x8*>(
          &Bs[(wn + j * 16 + lanelo) * 32 + laneq * 8]);
#pragma unroll
    for (int i = 0; i < 4; ++i)
#pragma unroll
      for (int j = 0; j < 4; ++j)
        acc[i][j] =
            __builtin_amdgcn_mfma_f32_16x16x32_f16(a[i], b[j], acc[i][j], 0, 0, 0);
    __syncthreads();
  }

#pragma unroll
  for (int i = 0; i < 4; ++i) {
#pragma unroll
    for (int r = 0; r < 4; ++r) {
      const int m = m0 + wm + i * 16 + laneq * 4 + r;
      const float wgt = w[(size_t)m * 8 + e];
      const float* erow = epsE + (size_t)m * 8192;
      float* orow = out + (size_t)m * 1024;
#pragma unroll
      for (int j = 0; j < 4; ++j) {
        const int d = n0 + wn + j * 16 + lanelo;
        const float t = acc[i][j][r] + bias[d];
        const float val =
            s ? wgt * erow[d] * __expf(0.5f * t) : wgt * t;
        unsafeAtomicAdd(&orow[d], val);
      }
    }
  }
}

// ---- gate finish ----------------------------------------------------------
__global__ __launch_bounds__(256) void gate_finish_kernel(
    const float* __restrict__ hg, const float* __restrict__ Wg2,
    const float* __restrict__ bg2, const float* __restrict__ gu,
    float* __restrict__ w) {
  const int lane = threadIdx.x & 63, wid = threadIdx.x >> 6;
  const int row = blockIdx.x * 4 + wid;
  const float* hrow = hg + (size_t)row * 2048;
  float acc[8] = {0.f, 0.f, 0.f, 0.f, 0.f, 0.f, 0.f, 0.f};
  for (int h = lane; h < 2048; h += 64) {
    const float hv = hrow[h];
    const float* wr = Wg2 + (size_t)h * 8;
#pragma unroll
    for (int e = 0; e < 8; ++e) acc[e] += hv * wr[e];
  }
#pragma unroll
  for (int off = 32; off > 0; off >>= 1) {
#pragma unroll
    for (int e = 0; e < 8; ++e) acc[e] += __shfl_down(acc[e], off);
  }
  if (lane == 0) {
    float z[8], zmax = -1e30f;
#pragma unroll
    for (int e = 0; e < 8; ++e) {
      const float u = gu[(size_t)row * 8 + e];
      const float g = -logf(-logf(u));
      z[e] = (acc[e] + bg2[e] + g) / 0.1f;
      zmax = fmaxf(zmax, z[e]);
    }
    float s = 0.f;
#pragma unroll
    for (int e = 0; e < 8; ++e) {
      z[e] = __expf(z[e] - zmax);
      s += z[e];
    }
    const float inv = 1.f / s;
#pragma unroll
    for (int e = 0; e < 8; ++e) w[(size_t)row * 8 + e] = z[e] * inv;
  }
}

// ---------------------------------------------------------------------------

extern "C" void kernel_launch(void* const* d_in, const int* in_sizes, int n_in,
                              void* d_out, int out_size, void* d_ws,
                              size_t ws_size, hipStream_t stream) {
  const float* x = (const float*)d_in[0];
  const float* gu = (const float*)d_in[1];
  const float* eps = (const float*)d_in[2];
  const float* Wg1 = (const float*)d_in[3];
  const float* bg1 = (const float*)d_in[4];
  const float* Wg2 = (const float*)d_in[5];
  const float* bg2 = (const float*)d_in[6];
  const float* Wm1 = (const float*)d_in[7];
  const float* bm1 = (const float*)d_in[8];
  const float* Wm2 = (const float*)d_in[9];
  const float* bm2 = (const float*)d_in[10];
  const float* Wv1 = (const float*)d_in[11];
  const float* bv1 = (const float*)d_in[12];
  const float* Wv2 = (const float*)d_in[13];
  const float* bv2 = (const float*)d_in[14];
  float* out = (float*)d_out;

  char* ws = (char*)d_ws;
  size_t off = 0;
  auto alloc = [&](size_t bytes) -> void* {
    void* p = ws + off;
    off = (off + bytes + 255) & ~(size_t)255;
    return p;
  };
  _Float16* Ax = (_Float16*)alloc(4096UL * 3072 * 2);        // 24 MB
  _Float16* Wg1t = (_Float16*)alloc(2048UL * 3072 * 2);      // 12 MB
  _Float16* W1t = (_Float16*)alloc(16UL * 2048 * 1024 * 2);  // 64 MB
  _Float16* W2t = (_Float16*)alloc(16UL * 1024 * 2048 * 2);  // 64 MB
  float* hg = (float*)alloc(4096UL * 2048 * 4);              // 32 MB
  float* wbuf = (float*)alloc(4096UL * 8 * 4);
  _Float16* hm = (_Float16*)alloc(8UL * 4096 * 2048 * 2);    // 128 MB
  _Float16* hv = (_Float16*)alloc(8UL * 4096 * 2048 * 2);    // 128 MB

  // 1) conversions + out zero-init
  zero_out_kernel<<<4096, 256, 0, stream>>>((float4*)out);
  split_x_kernel<<<4096 * 1024 / 256, 256, 0, stream>>>(x, Ax);
  split_transpose_wg1_kernel<<<dim3(2048 / 64, 1024 / 64), 256, 0, stream>>>(Wg1, Wg1t);
  transpose_f32_to_f16<<<dim3(2048 / 64, 1024 / 64, 8), 256, 0, stream>>>(
      Wm1, W1t, 1024, 2048);
  transpose_f32_to_f16<<<dim3(2048 / 64, 1024 / 64, 8), 256, 0, stream>>>(
      Wv1, W1t + 8UL * 2048 * 1024, 1024, 2048);
  transpose_f32_to_f16<<<dim3(1024 / 64, 2048 / 64, 8), 256, 0, stream>>>(
      Wm2, W2t, 2048, 1024);
  transpose_f32_to_f16<<<dim3(1024 / 64, 2048 / 64, 8), 256, 0, stream>>>(
      Wv2, W2t + 8UL * 1024 * 2048, 2048, 1024);

  // 2) gate
  gate_gemm1_kernel<<<dim3(2048 / 128, 4096 / 128), 256, 0, stream>>>(
      Ax, Wg1t, hg, bg1);
  gate_finish_kernel<<<4096 / 4, 256, 0, stream>>>(hg, Wg2, bg2, gu, wbuf);

  // 3) experts: one GEMM1 dispatch, one GEMM2+combine dispatch
  expert_gemm1_kernel<<<dim3(2048 / 128, 4096 / 128, 16), 256, 0, stream>>>(
      Ax, W1t, hm, hv, bm1, bv1);
  gemm2_combine_kernel<<<dim3(1024 / 128, 4096 / 128, 16), 256, 0, stream>>>(
      hm, hv, W2t, bm2, bv2, eps, wbuf, out);
}